// Round 18
// baseline (597.574 us; speedup 1.0000x reference)
//
#include <hip/hip_runtime.h>
#include <hip/hip_bf16.h>

#define BB 2048
#define NN 128
#define DD 256
#define HH 8
#define TT 64

typedef __bf16 bf16x8 __attribute__((ext_vector_type(8)));
typedef float f32x4 __attribute__((ext_vector_type(4)));

static __device__ __forceinline__ f32x4 mfma16(bf16x8 a, bf16x8 b, f32x4 c) {
  return __builtin_amdgcn_mfma_f32_16x16x32_bf16(a, b, c, 0, 0, 0);
}

static __device__ __forceinline__ f32x4 zero4() {
  f32x4 z = {0.f, 0.f, 0.f, 0.f};
  return z;
}

static __device__ __forceinline__ bf16x8 cvt8(const float* p) {
  const float4 x0 = *(const float4*)p;
  const float4 x1 = *(const float4*)(p + 4);
  bf16x8 r;
  r[0] = (__bf16)x0.x; r[1] = (__bf16)x0.y; r[2] = (__bf16)x0.z; r[3] = (__bf16)x0.w;
  r[4] = (__bf16)x1.x; r[5] = (__bf16)x1.y; r[6] = (__bf16)x1.z; r[7] = (__bf16)x1.w;
  return r;
}

static __device__ __forceinline__ unsigned pk2(float a, float b) {
  __bf16 x = (__bf16)a, y = (__bf16)b;
  unsigned short ux, uy;
  __builtin_memcpy(&ux, &x, 2);
  __builtin_memcpy(&uy, &y, 2);
  return (unsigned)ux | ((unsigned)uy << 16);
}

// 10*tanh(y) = 10 - 20/(1+e^{2y}); saturates correctly at +-10.
static __device__ __forceinline__ float fast_tanh10(float y) {
  const float e = __expf(2.f * y);
  return 10.f - 20.f * __builtin_amdgcn_rcpf(1.f + e);
}

// -------- fold1: 5 D x D products, one block per output row --------
__global__ void fold1(const float* __restrict__ Wq_m, const float* __restrict__ W_target,
                      const float* __restrict__ W_global, const float* __restrict__ Wk_m,
                      const float* __restrict__ W_K1, const float* __restrict__ Wv_m,
                      const float* __restrict__ W_V, const float* __restrict__ W_Q,
                      const float* __restrict__ Wo_m,
                      __bf16* __restrict__ WTQ, float* __restrict__ WGQT,
                      __bf16* __restrict__ WKH, __bf16* __restrict__ WVH,
                      float* __restrict__ WQO) {
  const int p = blockIdx.x >> 8;
  const int i = blockIdx.x & 255;
  const int t = threadIdx.x;
  __shared__ float arow[256];
  const float* A;
  const float* Bm;
  if (p == 0)      { A = Wq_m; Bm = W_target; }
  else if (p == 1) { A = Wq_m; Bm = W_global; }
  else if (p == 2) { A = Wk_m; Bm = W_K1; }
  else if (p == 3) { A = Wv_m; Bm = W_V; }
  else             { A = W_Q;  Bm = Wo_m; }
  arow[t] = A[i * 256 + t];
  __syncthreads();
  float acc = 0.f;
  for (int k = 0; k < 256; ++k) acc = fmaf(arow[k], Bm[k * 256 + t], acc);
  if (p == 0)      WTQ[i * 256 + t] = (__bf16)acc;
  else if (p == 1) WGQT[t * 256 + i] = acc;
  else if (p == 2) WKH[i * 256 + t] = (__bf16)acc;
  else if (p == 3) WVH[i * 256 + t] = (__bf16)acc;
  else             WQO[i * 256 + t] = acc;
}

// -------- fold2: WZL[j][i] = sum_d WQO[d][i] * W_K2[d][j]  (bf16) --------
__global__ void fold2(const float* __restrict__ WQO, const float* __restrict__ W_K2,
                      __bf16* __restrict__ WZL) {
  const int j = blockIdx.x;
  const int t = threadIdx.x;
  __shared__ float col[256];
  col[t] = W_K2[t * 256 + j];
  __syncthreads();
  float acc = 0.f;
  for (int d = 0; d < 256; ++d) acc = fmaf(WQO[d * 256 + t], col[d], acc);
  WZL[j * 256 + t] = (__bf16)acc;
}

// -------- gq: 8 b's per block; GQ[b][i] = sum_j WGQT[j][i] * ge[b][j] --------
__global__ void gq_kernel(const float* __restrict__ ge, const float* __restrict__ WGQT,
                          float* __restrict__ GQ) {
  const int b0 = blockIdx.x * 8;
  const int t = threadIdx.x;
  __shared__ float g[8][256];
#pragma unroll
  for (int i = 0; i < 8; ++i) g[i][t] = ge[(b0 + i) * 256 + t];
  __syncthreads();
  float acc[8] = {0.f, 0.f, 0.f, 0.f, 0.f, 0.f, 0.f, 0.f};
  for (int j = 0; j < 256; ++j) {
    const float wv = WGQT[j * 256 + t];
#pragma unroll
    for (int i = 0; i < 8; ++i) acc[i] = fmaf(wv, g[i][j], acc[i]);
  }
#pragma unroll
  for (int i = 0; i < 8; ++i) GQ[(b0 + i) * 256 + t] = acc[i];
}

// -------- kv: per b, 512 threads (8 waves). Stage E[b] bf16 once; K + V phases; --------
// then write gathered target rows Eg[b][t][:] = Es[tg[t]] (dense, for attn's Q GEMM).
// No Q GEMM here -> shorter serial chain, no gathered-MFMA LDS conflicts.
__global__ __launch_bounds__(512)
void kv_kernel(const float* __restrict__ E, const int* __restrict__ tg,
               const __bf16* __restrict__ WKH, const __bf16* __restrict__ WVH,
               __bf16* __restrict__ KH, __bf16* __restrict__ VT,
               __bf16* __restrict__ Eg) {
  const int b = blockIdx.x;
  const int tid = threadIdx.x;
  const int w = tid >> 6;
  const int l = tid & 63;
  const int lr = l & 15;
  const int lg = l >> 4;
  __shared__ __align__(16) __bf16 Es[128 * 264];
  __shared__ int tgs[64];
  if (tid < 64) tgs[tid] = tg[tid * BB + b];
  const float* Eb = E + (size_t)b * NN * DD;
#pragma unroll
  for (int it = 0; it < 8; ++it) {
    const int c = it * 512 + tid;
    const int row = c >> 5;
    const int c8 = c & 31;
    *(bf16x8*)&Es[row * 264 + c8 * 8] = cvt8(Eb + row * 256 + c8 * 8);
  }
  __syncthreads();

  // ---- Eg write-out: dense gathered rows (cheap; overlaps K-phase loads).
  {
    __bf16* Egb = Eg + (size_t)b * TT * DD;
#pragma unroll
    for (int it = 0; it < 4; ++it) {
      const int c = it * 512 + tid;
      const int row = c >> 5;
      const int c8 = c & 31;
      *(bf16x8*)(Egb + row * 256 + c8 * 8) = *(const bf16x8*)&Es[tgs[row] * 264 + c8 * 8];
    }
  }

  // ---- K phase: wave w owns cols [32w,32w+32) for all 128 nodes.
  {
    f32x4 acc[8][2];
#pragma unroll
    for (int mf = 0; mf < 8; ++mf)
#pragma unroll
      for (int nf = 0; nf < 2; ++nf) acc[mf][nf] = zero4();
    for (int kk = 0; kk < 8; ++kk) {
      bf16x8 aF[8], bF[2];
#pragma unroll
      for (int mf = 0; mf < 8; ++mf)
        aF[mf] = *(const bf16x8*)&Es[(mf * 16 + lr) * 264 + kk * 32 + lg * 8];
#pragma unroll
      for (int nf = 0; nf < 2; ++nf)
        bF[nf] = *(const bf16x8*)(WKH + (size_t)(w * 32 + nf * 16 + lr) * DD + kk * 32 + lg * 8);
#pragma unroll
      for (int mf = 0; mf < 8; ++mf)
#pragma unroll
        for (int nf = 0; nf < 2; ++nf) acc[mf][nf] = mfma16(aF[mf], bF[nf], acc[mf][nf]);
    }
    __bf16* KHb = KH + (size_t)b * NN * DD;
#pragma unroll
    for (int mf = 0; mf < 8; ++mf)
#pragma unroll
      for (int nf = 0; nf < 2; ++nf)
#pragma unroll
        for (int r = 0; r < 4; ++r)
          KHb[(mf * 16 + lg * 4 + r) * DD + w * 32 + nf * 16 + lr] = (__bf16)acc[mf][nf][r];
  }

  // ---- V phase (transposed): wave w owns dims [32w,32w+32).
  {
    f32x4 acc[2][8];
#pragma unroll
    for (int mf = 0; mf < 2; ++mf)
#pragma unroll
      for (int nf = 0; nf < 8; ++nf) acc[mf][nf] = zero4();
    for (int kk = 0; kk < 8; ++kk) {
      bf16x8 aW[2], bE[8];
#pragma unroll
      for (int mf = 0; mf < 2; ++mf)
        aW[mf] = *(const bf16x8*)(WVH + (size_t)(w * 32 + mf * 16 + lr) * DD + kk * 32 + lg * 8);
#pragma unroll
      for (int nf = 0; nf < 8; ++nf)
        bE[nf] = *(const bf16x8*)&Es[(nf * 16 + lr) * 264 + kk * 32 + lg * 8];
#pragma unroll
      for (int mf = 0; mf < 2; ++mf)
#pragma unroll
        for (int nf = 0; nf < 8; ++nf) acc[mf][nf] = mfma16(aW[mf], bE[nf], acc[mf][nf]);
    }
    __bf16* VTb = VT + (size_t)b * DD * NN;
#pragma unroll
    for (int mf = 0; mf < 2; ++mf)
#pragma unroll
      for (int nf = 0; nf < 8; ++nf)
#pragma unroll
        for (int r = 0; r < 4; ++r)
          VTb[(w * 32 + mf * 16 + lg * 4 + r) * NN + nf * 16 + lr] = (__bf16)acc[mf][nf][r];
  }
}

// -------- attn6: per (b, head-pair), XCD-clustered. Q-GEMM with COALESCED Eg rows --------
// (R16's validated layout, minus the random gather) overlaps KHs/VTs staging.
// Q -> per-wave Ps buf -> aq; then QK swapped / softmax / PV (R14 inner structure).
__global__ __launch_bounds__(256)
void attn6_kernel(const __bf16* __restrict__ Eg, const __bf16* __restrict__ WTQ,
                  const float* __restrict__ GQ, const __bf16* __restrict__ KH,
                  const __bf16* __restrict__ VT, __bf16* __restrict__ HO) {
  const int j = (blockIdx.x & 7) * ((BB * 4) / 8) + (blockIdx.x >> 3);
  const int b = j >> 2;
  const int c0 = (j & 3) * 64;  // Q/dim column window of this head pair
  const int tid = threadIdx.x;
  const int w = tid >> 6;
  const int l = tid & 63;
  const int lr = l & 15;
  const int lg = l >> 4;
  const int T0 = w * 16;

  __shared__ __align__(16) __bf16 KHs[128 * 72];  // [node][64 dims]
  __shared__ __align__(16) __bf16 VTs[64 * 136];  // [dim][128 nodes]
  __shared__ __align__(16) __bf16 Ps[4][16 * 136];

  const __bf16* Egb = Eg + (size_t)b * TT * DD;
  const __bf16* KHb = KH + (size_t)b * NN * DD;
  const __bf16* VTb = VT + (size_t)b * DD * NN;
  __bf16* myp = Ps[w];

  // ---- Stage KHs/VTs (loads issue first; Q-GEMM below hides their latency).
#pragma unroll
  for (int it = 0; it < 4; ++it) {  // KHs: 128 rows x 8 chunks
    const int c = it * 256 + tid;
    const int row = c >> 3;
    const int c8 = c & 7;
    *(bf16x8*)&KHs[row * 72 + c8 * 8] = *(const bf16x8*)(KHb + (size_t)row * DD + c0 + c8 * 8);
  }
#pragma unroll
  for (int it = 0; it < 4; ++it) {  // VTs: 64 rows x 16 chunks
    const int c = it * 256 + tid;
    const int row = c >> 4;
    const int c8 = c & 15;
    *(bf16x8*)&VTs[row * 136 + c8 * 8] =
        *(const bf16x8*)(VTb + (size_t)(c0 + row) * NN + c8 * 8);
  }

  // ---- Q-GEMM: wave w computes Q[T0..T0+16][c0..c0+64) = Eg rows @ WTQ^T + GQ.
  {
    f32x4 qa[4] = {zero4(), zero4(), zero4(), zero4()};
    for (int kk = 0; kk < 8; ++kk) {
      const bf16x8 aF = *(const bf16x8*)(Egb + (size_t)(T0 + lr) * DD + kk * 32 + lg * 8);
#pragma unroll
      for (int nf = 0; nf < 4; ++nf) {
        const bf16x8 bF =
            *(const bf16x8*)(WTQ + (size_t)(c0 + nf * 16 + lr) * DD + kk * 32 + lg * 8);
        qa[nf] = mfma16(aF, bF, qa[nf]);
      }
    }
#pragma unroll
    for (int nf = 0; nf < 4; ++nf) {
      const float g = GQ[b * DD + c0 + nf * 16 + lr];
#pragma unroll
      for (int r = 0; r < 4; ++r)
        myp[(lg * 4 + r) * 72 + nf * 16 + lr] = (__bf16)(qa[nf][r] + g);
    }
  }
  // aq fragments for both heads (row t-local = lr); same-wave in-order DS.
  bf16x8 aq[2];
#pragma unroll
  for (int h = 0; h < 2; ++h) aq[h] = *(const bf16x8*)&myp[lr * 72 + h * 32 + lg * 8];
  __syncthreads();

  __bf16* HOb = HO + (size_t)b * TT * DD + c0;

#pragma unroll
  for (int h = 0; h < 2; ++h) {
    // QK swapped: lane holds S[node = nf*16+lg*4+r][t = T0+lr]
    f32x4 s[8];
#pragma unroll
    for (int nf = 0; nf < 8; ++nf)
      s[nf] = mfma16(*(const bf16x8*)&KHs[(nf * 16 + lr) * 72 + h * 32 + lg * 8], aq[h], zero4());

    float mx = -1e30f;
#pragma unroll
    for (int nf = 0; nf < 8; ++nf)
#pragma unroll
      for (int r = 0; r < 4; ++r) mx = fmaxf(mx, s[nf][r]);
    mx = fmaxf(mx, __shfl_xor(mx, 16));
    mx = fmaxf(mx, __shfl_xor(mx, 32));

    float sm = 0.f;
    uint2 evp[8];
#pragma unroll
    for (int nf = 0; nf < 8; ++nf) {
      const float e0 = __expf((s[nf][0] - mx) * 0.17677669529663687f);
      const float e1 = __expf((s[nf][1] - mx) * 0.17677669529663687f);
      const float e2 = __expf((s[nf][2] - mx) * 0.17677669529663687f);
      const float e3 = __expf((s[nf][3] - mx) * 0.17677669529663687f);
      sm += (e0 + e1) + (e2 + e3);
      evp[nf].x = pk2(e0, e1);
      evp[nf].y = pk2(e2, e3);
    }
    sm += __shfl_xor(sm, 16);
    sm += __shfl_xor(sm, 32);

    // P row t-local=lr: nodes nf*16 + lg*4 .. +4 (same-wave in-order DS)
#pragma unroll
    for (int nf = 0; nf < 8; ++nf)
      *(uint2*)&myp[lr * 136 + nf * 16 + lg * 4] = evp[nf];

    // PV: A = P rows (LDS), B = VTs dim-rows (LDS)
    f32x4 o0 = zero4(), o1 = zero4();
#pragma unroll
    for (int kk = 0; kk < 4; ++kk) {
      const bf16x8 ap = *(const bf16x8*)&myp[lr * 136 + kk * 32 + lg * 8];
      o0 = mfma16(ap, *(const bf16x8*)&VTs[(h * 32 + lr) * 136 + kk * 32 + lg * 8], o0);
      o1 = mfma16(ap, *(const bf16x8*)&VTs[(h * 32 + 16 + lr) * 136 + kk * 32 + lg * 8], o1);
    }
#pragma unroll
    for (int r = 0; r < 4; ++r) {
      const float inv = __builtin_amdgcn_rcpf(__shfl(sm, lg * 4 + r));
      HOb[(size_t)(T0 + lg * 4 + r) * DD + h * 32 + lr] = (__bf16)(o0[r] * inv);
      HOb[(size_t)(T0 + lg * 4 + r) * DD + h * 32 + 16 + lr] = (__bf16)(o1[r] * inv);
    }
  }
}

// -------- zlog2: per b. Z = HO @ WZL^T -> Zs; logits swapped (lane owns t-row); --------
// E read as f32 + cvt (L3 absorbs re-reads).
__global__ __launch_bounds__(256)
void zlog2_kernel(const float* __restrict__ E, const __bf16* __restrict__ HO,
                  const __bf16* __restrict__ WZL, const int* __restrict__ MK,
                  float* __restrict__ out) {
  const int b = blockIdx.x;
  const int tid = threadIdx.x;
  const int w = tid >> 6;
  const int l = tid & 63;
  const int lr = l & 15;
  const int lg = l >> 4;
  const int T0 = w * 16;
  __shared__ __align__(16) __bf16 Zs[64 * 264];
  __shared__ float red[4];

  const float* Eb = E + (size_t)b * NN * DD;
  const __bf16* HOb = HO + (size_t)b * TT * DD;

  // Z GEMM: wave w owns cols [64w,64w+64) for all 64 t-rows.
  {
    f32x4 acc[4][4];
#pragma unroll
    for (int mf = 0; mf < 4; ++mf)
#pragma unroll
      for (int nf = 0; nf < 4; ++nf) acc[mf][nf] = zero4();
    for (int kk = 0; kk < 8; ++kk) {
      bf16x8 aF[4], bF[4];
#pragma unroll
      for (int mf = 0; mf < 4; ++mf)
        aF[mf] = *(const bf16x8*)(HOb + (size_t)(mf * 16 + lr) * DD + kk * 32 + lg * 8);
#pragma unroll
      for (int nf = 0; nf < 4; ++nf)
        bF[nf] = *(const bf16x8*)(WZL + (size_t)(w * 64 + nf * 16 + lr) * DD + kk * 32 + lg * 8);
#pragma unroll
      for (int mf = 0; mf < 4; ++mf)
#pragma unroll
        for (int nf = 0; nf < 4; ++nf) acc[mf][nf] = mfma16(aF[mf], bF[nf], acc[mf][nf]);
    }
#pragma unroll
    for (int mf = 0; mf < 4; ++mf)
#pragma unroll
      for (int nf = 0; nf < 4; ++nf)
#pragma unroll
        for (int r = 0; r < 4; ++r)
          Zs[(mf * 16 + lg * 4 + r) * 264 + w * 64 + nf * 16 + lr] = (__bf16)acc[mf][nf][r];
  }
  __syncthreads();

  // logits swapped: A = E nodes (cvt f32), B = Zs t-rows. Lane owns t=T0+lr.
  {
    f32x4 sa[8];
#pragma unroll
    for (int nf = 0; nf < 8; ++nf) sa[nf] = zero4();
    for (int kk = 0; kk < 8; ++kk) {
      const bf16x8 bZ = *(const bf16x8*)&Zs[(T0 + lr) * 264 + kk * 32 + lg * 8];
#pragma unroll
      for (int nf = 0; nf < 8; ++nf) {
        const bf16x8 aE = cvt8(Eb + (size_t)(nf * 16 + lr) * DD + kk * 32 + lg * 8);
        sa[nf] = mfma16(aE, bZ, sa[nf]);
      }
    }
    const int t = T0 + lr;
    float xs[8][4];
    float mx = -3e38f;
#pragma unroll
    for (int nf = 0; nf < 8; ++nf) {
      const int4 mk4 = *(const int4*)(MK + ((size_t)t * BB + b) * NN + nf * 16 + lg * 4);
      xs[nf][0] = fast_tanh10(sa[nf][0] * 0.0625f) - (float)mk4.x * 1e9f;
      xs[nf][1] = fast_tanh10(sa[nf][1] * 0.0625f) - (float)mk4.y * 1e9f;
      xs[nf][2] = fast_tanh10(sa[nf][2] * 0.0625f) - (float)mk4.z * 1e9f;
      xs[nf][3] = fast_tanh10(sa[nf][3] * 0.0625f) - (float)mk4.w * 1e9f;
      mx = fmaxf(mx, fmaxf(fmaxf(xs[nf][0], xs[nf][1]), fmaxf(xs[nf][2], xs[nf][3])));
    }
    mx = fmaxf(mx, __shfl_xor(mx, 16));
    mx = fmaxf(mx, __shfl_xor(mx, 32));
    float sm = 0.f;
#pragma unroll
    for (int nf = 0; nf < 8; ++nf)
#pragma unroll
      for (int r = 0; r < 4; ++r) sm += __expf(xs[nf][r] - mx);
    sm += __shfl_xor(sm, 16);
    sm += __shfl_xor(sm, 32);
    float part = logf(sm);
    part += __shfl_xor(part, 1);
    part += __shfl_xor(part, 2);
    part += __shfl_xor(part, 4);
    part += __shfl_xor(part, 8);
    if (l == 0) red[w] = part;
  }
  __syncthreads();
  if (tid == 0) out[b] = -(red[0] + red[1] + red[2] + red[3]);
}

extern "C" void kernel_launch(void* const* d_in, const int* in_sizes, int n_in,
                              void* d_out, int out_size, void* d_ws, size_t ws_size,
                              hipStream_t stream) {
  (void)in_sizes; (void)n_in; (void)out_size; (void)ws_size;
  const float* node_emb  = (const float*)d_in[0];
  const float* graph_emb = (const float*)d_in[1];
  const float* W_target  = (const float*)d_in[2];
  const float* W_global  = (const float*)d_in[3];
  const float* W_K1      = (const float*)d_in[4];
  const float* W_K2      = (const float*)d_in[5];
  const float* W_Q       = (const float*)d_in[6];
  const float* W_V       = (const float*)d_in[7];
  const float* Wq_m      = (const float*)d_in[8];
  const float* Wk_m      = (const float*)d_in[9];
  const float* Wv_m      = (const float*)d_in[10];
  const float* Wo_m      = (const float*)d_in[11];
  const int* targets     = (const int*)d_in[12];
  const int* masks       = (const int*)d_in[13];

  char* p = (char*)d_ws;
  __bf16* KH  = (__bf16*)p; p += (size_t)BB * NN * DD * 2;  // 134 MB
  __bf16* VT  = (__bf16*)p; p += (size_t)BB * DD * NN * 2;  // 134 MB
  __bf16* HO  = (__bf16*)p; p += (size_t)BB * TT * DD * 2;  // 67 MB
  __bf16* Eg  = (__bf16*)p; p += (size_t)BB * TT * DD * 2;  // 67 MB
  __bf16* WTQ = (__bf16*)p; p += 256 * 256 * 2;
  __bf16* WKH = (__bf16*)p; p += 256 * 256 * 2;
  __bf16* WVH = (__bf16*)p; p += 256 * 256 * 2;
  __bf16* WZL = (__bf16*)p; p += 256 * 256 * 2;
  float* WGQT = (float*)p;  p += 256 * 256 * 4;
  float* WQO  = (float*)p;  p += 256 * 256 * 4;
  float* GQ   = (float*)p;  p += (size_t)BB * DD * 4;

  fold1<<<1280, 256, 0, stream>>>(Wq_m, W_target, W_global, Wk_m, W_K1, Wv_m, W_V, W_Q, Wo_m,
                                  WTQ, WGQT, WKH, WVH, WQO);
  fold2<<<256, 256, 0, stream>>>(WQO, W_K2, WZL);
  gq_kernel<<<BB / 8, 256, 0, stream>>>(graph_emb, WGQT, GQ);
  kv_kernel<<<BB, 512, 0, stream>>>(node_emb, targets, WKH, WVH, KH, VT, Eg);
  attn6_kernel<<<BB * 4, 256, 0, stream>>>(Eg, WTQ, GQ, KH, VT, HO);
  zlog2_kernel<<<BB, 256, 0, stream>>>(node_emb, HO, WZL, masks, (float*)d_out);
}

// Round 19
// 519.571 us; speedup vs baseline: 1.1501x; 1.1501x over previous
//
#include <hip/hip_runtime.h>
#include <hip/hip_bf16.h>

#define BB 2048
#define NN 128
#define DD 256
#define HH 8
#define TT 64

typedef __bf16 bf16x8 __attribute__((ext_vector_type(8)));
typedef float f32x4 __attribute__((ext_vector_type(4)));

static __device__ __forceinline__ f32x4 mfma16(bf16x8 a, bf16x8 b, f32x4 c) {
  return __builtin_amdgcn_mfma_f32_16x16x32_bf16(a, b, c, 0, 0, 0);
}

static __device__ __forceinline__ f32x4 zero4() {
  f32x4 z = {0.f, 0.f, 0.f, 0.f};
  return z;
}

static __device__ __forceinline__ bf16x8 cvt8(const float* p) {
  const float4 x0 = *(const float4*)p;
  const float4 x1 = *(const float4*)(p + 4);
  bf16x8 r;
  r[0] = (__bf16)x0.x; r[1] = (__bf16)x0.y; r[2] = (__bf16)x0.z; r[3] = (__bf16)x0.w;
  r[4] = (__bf16)x1.x; r[5] = (__bf16)x1.y; r[6] = (__bf16)x1.z; r[7] = (__bf16)x1.w;
  return r;
}

static __device__ __forceinline__ unsigned pk2(float a, float b) {
  __bf16 x = (__bf16)a, y = (__bf16)b;
  unsigned short ux, uy;
  __builtin_memcpy(&ux, &x, 2);
  __builtin_memcpy(&uy, &y, 2);
  return (unsigned)ux | ((unsigned)uy << 16);
}

static __device__ __forceinline__ uint2 pk4(const f32x4 v) {
  uint2 r;
  r.x = pk2(v[0], v[1]);
  r.y = pk2(v[2], v[3]);
  return r;
}

// 10*tanh(y) = 10 - 20/(1+e^{2y}); saturates correctly at +-10.
static __device__ __forceinline__ float fast_tanh10(float y) {
  const float e = __expf(2.f * y);
  return 10.f - 20.f * __builtin_amdgcn_rcpf(1.f + e);
}

// -------- fold1: 5 D x D products, one block per output row --------
__global__ void fold1(const float* __restrict__ Wq_m, const float* __restrict__ W_target,
                      const float* __restrict__ W_global, const float* __restrict__ Wk_m,
                      const float* __restrict__ W_K1, const float* __restrict__ Wv_m,
                      const float* __restrict__ W_V, const float* __restrict__ W_Q,
                      const float* __restrict__ Wo_m,
                      __bf16* __restrict__ WTQ, float* __restrict__ WGQT,
                      __bf16* __restrict__ WKH, __bf16* __restrict__ WVH,
                      float* __restrict__ WQO) {
  const int p = blockIdx.x >> 8;
  const int i = blockIdx.x & 255;
  const int t = threadIdx.x;
  __shared__ float arow[256];
  const float* A;
  const float* Bm;
  if (p == 0)      { A = Wq_m; Bm = W_target; }
  else if (p == 1) { A = Wq_m; Bm = W_global; }
  else if (p == 2) { A = Wk_m; Bm = W_K1; }
  else if (p == 3) { A = Wv_m; Bm = W_V; }
  else             { A = W_Q;  Bm = Wo_m; }
  arow[t] = A[i * 256 + t];
  __syncthreads();
  float acc = 0.f;
  for (int k = 0; k < 256; ++k) acc = fmaf(arow[k], Bm[k * 256 + t], acc);
  if (p == 0)      WTQ[i * 256 + t] = (__bf16)acc;
  else if (p == 1) WGQT[t * 256 + i] = acc;
  else if (p == 2) WKH[i * 256 + t] = (__bf16)acc;
  else if (p == 3) WVH[i * 256 + t] = (__bf16)acc;
  else             WQO[i * 256 + t] = acc;
}

// -------- fold2: WZL[j][i] = sum_d WQO[d][i] * W_K2[d][j]  (bf16) --------
__global__ void fold2(const float* __restrict__ WQO, const float* __restrict__ W_K2,
                      __bf16* __restrict__ WZL) {
  const int j = blockIdx.x;
  const int t = threadIdx.x;
  __shared__ float col[256];
  col[t] = W_K2[t * 256 + j];
  __syncthreads();
  float acc = 0.f;
  for (int d = 0; d < 256; ++d) acc = fmaf(WQO[d * 256 + t], col[d], acc);
  WZL[j * 256 + t] = (__bf16)acc;
}

// -------- gq: 8 b's per block; GQ[b][i] = sum_j WGQT[j][i] * ge[b][j] --------
__global__ void gq_kernel(const float* __restrict__ ge, const float* __restrict__ WGQT,
                          float* __restrict__ GQ) {
  const int b0 = blockIdx.x * 8;
  const int t = threadIdx.x;
  __shared__ float g[8][256];
#pragma unroll
  for (int i = 0; i < 8; ++i) g[i][t] = ge[(b0 + i) * 256 + t];
  __syncthreads();
  float acc[8] = {0.f, 0.f, 0.f, 0.f, 0.f, 0.f, 0.f, 0.f};
  for (int j = 0; j < 256; ++j) {
    const float wv = WGQT[j * 256 + t];
#pragma unroll
    for (int i = 0; i < 8; ++i) acc[i] = fmaf(wv, g[i][j], acc[i]);
  }
#pragma unroll
  for (int i = 0; i < 8; ++i) GQ[(b0 + i) * 256 + t] = acc[i];
}

// -------- kvq (R17 structure + swapped-operand epilogues => uint2 stores). --------
// D[i][j] mapping: i (from X rows) = lg*4+r, j (from Y rows) = lr. Swapping args
// puts a lane's 4 acc values at 4 CONSECUTIVE columns of one row -> packed stores.
__global__ __launch_bounds__(512)
void kvq_kernel(const float* __restrict__ E, const int* __restrict__ tg,
                const __bf16* __restrict__ WKH, const __bf16* __restrict__ WVH,
                const __bf16* __restrict__ WTQ, const float* __restrict__ GQ,
                __bf16* __restrict__ KH, __bf16* __restrict__ VT,
                __bf16* __restrict__ Qb) {
  const int b = blockIdx.x;
  const int tid = threadIdx.x;
  const int w = tid >> 6;
  const int l = tid & 63;
  const int lr = l & 15;
  const int lg = l >> 4;
  __shared__ __align__(16) __bf16 Es[128 * 264];
  __shared__ int tgs[64];
  if (tid < 64) tgs[tid] = tg[tid * BB + b];
  const float* Eb = E + (size_t)b * NN * DD;
#pragma unroll
  for (int it = 0; it < 8; ++it) {
    const int c = it * 512 + tid;
    const int row = c >> 5;
    const int c8 = c & 31;
    *(bf16x8*)&Es[row * 264 + c8 * 8] = cvt8(Eb + row * 256 + c8 * 8);
  }
  __syncthreads();

  // ---- K phase (swapped): acc[mf][nf] = D[kcol i][node j];
  //      KH[node = mf*16+lr][kcol = w*32+nf*16+lg*4+r] -> uint2.
  {
    f32x4 acc[8][2];
#pragma unroll
    for (int mf = 0; mf < 8; ++mf)
#pragma unroll
      for (int nf = 0; nf < 2; ++nf) acc[mf][nf] = zero4();
    for (int kk = 0; kk < 8; ++kk) {
      bf16x8 aF[8], bF[2];
#pragma unroll
      for (int mf = 0; mf < 8; ++mf)
        aF[mf] = *(const bf16x8*)&Es[(mf * 16 + lr) * 264 + kk * 32 + lg * 8];
#pragma unroll
      for (int nf = 0; nf < 2; ++nf)
        bF[nf] = *(const bf16x8*)(WKH + (size_t)(w * 32 + nf * 16 + lr) * DD + kk * 32 + lg * 8);
#pragma unroll
      for (int mf = 0; mf < 8; ++mf)
#pragma unroll
        for (int nf = 0; nf < 2; ++nf) acc[mf][nf] = mfma16(bF[nf], aF[mf], acc[mf][nf]);
    }
    __bf16* KHb = KH + (size_t)b * NN * DD;
#pragma unroll
    for (int mf = 0; mf < 8; ++mf)
#pragma unroll
      for (int nf = 0; nf < 2; ++nf)
        *(uint2*)(KHb + (size_t)(mf * 16 + lr) * DD + w * 32 + nf * 16 + lg * 4) =
            pk4(acc[mf][nf]);
  }

  // ---- V phase (swapped): acc[mf][nf] = D[node i][dim j];
  //      VT[dim = w*32+mf*16+lr][node = nf*16+lg*4+r] -> uint2.
  {
    f32x4 acc[2][8];
#pragma unroll
    for (int mf = 0; mf < 2; ++mf)
#pragma unroll
      for (int nf = 0; nf < 8; ++nf) acc[mf][nf] = zero4();
    for (int kk = 0; kk < 8; ++kk) {
      bf16x8 aW[2], bE[8];
#pragma unroll
      for (int mf = 0; mf < 2; ++mf)
        aW[mf] = *(const bf16x8*)(WVH + (size_t)(w * 32 + mf * 16 + lr) * DD + kk * 32 + lg * 8);
#pragma unroll
      for (int nf = 0; nf < 8; ++nf)
        bE[nf] = *(const bf16x8*)&Es[(nf * 16 + lr) * 264 + kk * 32 + lg * 8];
#pragma unroll
      for (int mf = 0; mf < 2; ++mf)
#pragma unroll
        for (int nf = 0; nf < 8; ++nf) acc[mf][nf] = mfma16(bE[nf], aW[mf], acc[mf][nf]);
    }
    __bf16* VTb = VT + (size_t)b * DD * NN;
#pragma unroll
    for (int mf = 0; mf < 2; ++mf)
#pragma unroll
      for (int nf = 0; nf < 8; ++nf)
        *(uint2*)(VTb + (size_t)(w * 32 + mf * 16 + lr) * NN + nf * 16 + lg * 4) =
            pk4(acc[mf][nf]);
  }

  // ---- Q phase (swapped): acc[mf][nf] = D[qcol i][t j];
  //      Qb[t = mf*16+lr][qcol = w*32+nf*16+lg*4+r] -> uint2 (GQ bias via float4).
  {
    f32x4 acc[4][2];
#pragma unroll
    for (int mf = 0; mf < 4; ++mf)
#pragma unroll
      for (int nf = 0; nf < 2; ++nf) acc[mf][nf] = zero4();
    int rowoff[4];
#pragma unroll
    for (int mf = 0; mf < 4; ++mf) rowoff[mf] = tgs[mf * 16 + lr] * 264;
    for (int kk = 0; kk < 8; ++kk) {
      bf16x8 aF[4], bF[2];
#pragma unroll
      for (int mf = 0; mf < 4; ++mf)
        aF[mf] = *(const bf16x8*)&Es[rowoff[mf] + kk * 32 + lg * 8];
#pragma unroll
      for (int nf = 0; nf < 2; ++nf)
        bF[nf] = *(const bf16x8*)(WTQ + (size_t)(w * 32 + nf * 16 + lr) * DD + kk * 32 + lg * 8);
#pragma unroll
      for (int mf = 0; mf < 4; ++mf)
#pragma unroll
        for (int nf = 0; nf < 2; ++nf) acc[mf][nf] = mfma16(bF[nf], aF[mf], acc[mf][nf]);
    }
#pragma unroll
    for (int nf = 0; nf < 2; ++nf) {
      const float4 g4 = *(const float4*)(GQ + b * DD + w * 32 + nf * 16 + lg * 4);
#pragma unroll
      for (int mf = 0; mf < 4; ++mf) {
        f32x4 v = acc[mf][nf];
        v[0] += g4.x; v[1] += g4.y; v[2] += g4.z; v[3] += g4.w;
        *(uint2*)(Qb + ((size_t)b * TT + mf * 16 + lr) * DD + w * 32 + nf * 16 + lg * 4) =
            pk4(v);
      }
    }
  }
}

// -------- attn4: per (b, head-pair), XCD-clustered. Stage KH/VT in LDS (1 barrier); --------
// aq hoisted. QK swapped; PV ALSO swapped: lane holds O[dim = lg*4+r][t = lr] ->
// uint2 HO stores + lane-local 1/sm (no shuffle).
__global__ __launch_bounds__(256)
void attn4_kernel(const __bf16* __restrict__ Qb, const __bf16* __restrict__ KH,
                  const __bf16* __restrict__ VT, __bf16* __restrict__ HO) {
  const int j = (blockIdx.x & 7) * ((BB * 4) / 8) + (blockIdx.x >> 3);
  const int b = j >> 2;
  const int c0 = (j & 3) * 64;  // dim window of this head pair
  const int tid = threadIdx.x;
  const int w = tid >> 6;
  const int l = tid & 63;
  const int lr = l & 15;
  const int lg = l >> 4;
  const int T0 = w * 16;

  __shared__ __align__(16) __bf16 KHs[128 * 72];  // [node][64 dims]
  __shared__ __align__(16) __bf16 VTs[64 * 136];  // [dim][128 nodes]
  __shared__ __align__(16) __bf16 Ps[4][16 * 136];

  const __bf16* KHb = KH + (size_t)b * NN * DD;
  const __bf16* VTb = VT + (size_t)b * DD * NN;

  // hoist both heads' Q fragments; loads overlap the staging below.
  bf16x8 aq[2];
#pragma unroll
  for (int h = 0; h < 2; ++h)
    aq[h] = *(const bf16x8*)(Qb + ((size_t)b * TT + T0 + lr) * DD + c0 + h * 32 + lg * 8);

#pragma unroll
  for (int it = 0; it < 4; ++it) {  // KHs: 128 rows x 8 chunks
    const int c = it * 256 + tid;
    const int row = c >> 3;
    const int c8 = c & 7;
    *(bf16x8*)&KHs[row * 72 + c8 * 8] = *(const bf16x8*)(KHb + (size_t)row * DD + c0 + c8 * 8);
  }
#pragma unroll
  for (int it = 0; it < 4; ++it) {  // VTs: 64 rows x 16 chunks
    const int c = it * 256 + tid;
    const int row = c >> 4;
    const int c8 = c & 15;
    *(bf16x8*)&VTs[row * 136 + c8 * 8] =
        *(const bf16x8*)(VTb + (size_t)(c0 + row) * NN + c8 * 8);
  }
  __syncthreads();

  __bf16* myp = Ps[w];
  __bf16* HOb = HO + (size_t)b * TT * DD + c0;

#pragma unroll
  for (int h = 0; h < 2; ++h) {
    // QK swapped: lane holds S[node = nf*16+lg*4+r][t = T0+lr]
    f32x4 s[8];
#pragma unroll
    for (int nf = 0; nf < 8; ++nf)
      s[nf] = mfma16(*(const bf16x8*)&KHs[(nf * 16 + lr) * 72 + h * 32 + lg * 8], aq[h], zero4());

    float mx = -1e30f;
#pragma unroll
    for (int nf = 0; nf < 8; ++nf)
#pragma unroll
      for (int r = 0; r < 4; ++r) mx = fmaxf(mx, s[nf][r]);
    mx = fmaxf(mx, __shfl_xor(mx, 16));
    mx = fmaxf(mx, __shfl_xor(mx, 32));

    float sm = 0.f;
    uint2 evp[8];
#pragma unroll
    for (int nf = 0; nf < 8; ++nf) {
      const float e0 = __expf((s[nf][0] - mx) * 0.17677669529663687f);
      const float e1 = __expf((s[nf][1] - mx) * 0.17677669529663687f);
      const float e2 = __expf((s[nf][2] - mx) * 0.17677669529663687f);
      const float e3 = __expf((s[nf][3] - mx) * 0.17677669529663687f);
      sm += (e0 + e1) + (e2 + e3);
      evp[nf].x = pk2(e0, e1);
      evp[nf].y = pk2(e2, e3);
    }
    sm += __shfl_xor(sm, 16);
    sm += __shfl_xor(sm, 32);

    // P row t-local=lr: nodes nf*16 + lg*4 .. +4 (same-wave in-order DS)
#pragma unroll
    for (int nf = 0; nf < 8; ++nf)
      *(uint2*)&myp[lr * 136 + nf * 16 + lg * 4] = evp[nf];

    // PV swapped: o = D[dim i][t j]; lane holds t = T0+lr, dims h*32(+16)+lg*4+r.
    f32x4 o0 = zero4(), o1 = zero4();
#pragma unroll
    for (int kk = 0; kk < 4; ++kk) {
      const bf16x8 ap = *(const bf16x8*)&myp[lr * 136 + kk * 32 + lg * 8];
      o0 = mfma16(*(const bf16x8*)&VTs[(h * 32 + lr) * 136 + kk * 32 + lg * 8], ap, o0);
      o1 = mfma16(*(const bf16x8*)&VTs[(h * 32 + 16 + lr) * 136 + kk * 32 + lg * 8], ap, o1);
    }
    const float inv = __builtin_amdgcn_rcpf(sm);  // sm is lane-local (t = T0+lr)
    f32x4 v0 = o0, v1 = o1;
#pragma unroll
    for (int r = 0; r < 4; ++r) { v0[r] *= inv; v1[r] *= inv; }
    *(uint2*)(HOb + (size_t)(T0 + lr) * DD + h * 32 + lg * 4) = pk4(v0);
    *(uint2*)(HOb + (size_t)(T0 + lr) * DD + h * 32 + 16 + lg * 4) = pk4(v1);
  }
}

// -------- zlog2: per b. Z = HO @ WZL^T (swapped -> uint2 ds_write) -> Zs; --------
// logits swapped (lane owns t-row); E read as f32 + cvt.
__global__ __launch_bounds__(256)
void zlog2_kernel(const float* __restrict__ E, const __bf16* __restrict__ HO,
                  const __bf16* __restrict__ WZL, const int* __restrict__ MK,
                  float* __restrict__ out) {
  const int b = blockIdx.x;
  const int tid = threadIdx.x;
  const int w = tid >> 6;
  const int l = tid & 63;
  const int lr = l & 15;
  const int lg = l >> 4;
  const int T0 = w * 16;
  __shared__ __align__(16) __bf16 Zs[64 * 264];
  __shared__ float red[4];

  const float* Eb = E + (size_t)b * NN * DD;
  const __bf16* HOb = HO + (size_t)b * TT * DD;

  // Z GEMM (swapped): acc[mf][nf] = D[zcol i][t j];
  // Zs[t = mf*16+lr][zcol = w*64+nf*16+lg*4+r] -> uint2 ds_write.
  {
    f32x4 acc[4][4];
#pragma unroll
    for (int mf = 0; mf < 4; ++mf)
#pragma unroll
      for (int nf = 0; nf < 4; ++nf) acc[mf][nf] = zero4();
    for (int kk = 0; kk < 8; ++kk) {
      bf16x8 aF[4], bF[4];
#pragma unroll
      for (int mf = 0; mf < 4; ++mf)
        aF[mf] = *(const bf16x8*)(HOb + (size_t)(mf * 16 + lr) * DD + kk * 32 + lg * 8);
#pragma unroll
      for (int nf = 0; nf < 4; ++nf)
        bF[nf] = *(const bf16x8*)(WZL + (size_t)(w * 64 + nf * 16 + lr) * DD + kk * 32 + lg * 8);
#pragma unroll
      for (int mf = 0; mf < 4; ++mf)
#pragma unroll
        for (int nf = 0; nf < 4; ++nf) acc[mf][nf] = mfma16(bF[nf], aF[mf], acc[mf][nf]);
    }
#pragma unroll
    for (int mf = 0; mf < 4; ++mf)
#pragma unroll
      for (int nf = 0; nf < 4; ++nf)
        *(uint2*)&Zs[(mf * 16 + lr) * 264 + w * 64 + nf * 16 + lg * 4] = pk4(acc[mf][nf]);
  }
  __syncthreads();

  // logits swapped: A = E nodes (cvt f32), B = Zs t-rows. Lane owns t=T0+lr.
  {
    f32x4 sa[8];
#pragma unroll
    for (int nf = 0; nf < 8; ++nf) sa[nf] = zero4();
    for (int kk = 0; kk < 8; ++kk) {
      const bf16x8 bZ = *(const bf16x8*)&Zs[(T0 + lr) * 264 + kk * 32 + lg * 8];
#pragma unroll
      for (int nf = 0; nf < 8; ++nf) {
        const bf16x8 aE = cvt8(Eb + (size_t)(nf * 16 + lr) * DD + kk * 32 + lg * 8);
        sa[nf] = mfma16(aE, bZ, sa[nf]);
      }
    }
    const int t = T0 + lr;
    float xs[8][4];
    float mx = -3e38f;
#pragma unroll
    for (int nf = 0; nf < 8; ++nf) {
      const int4 mk4 = *(const int4*)(MK + ((size_t)t * BB + b) * NN + nf * 16 + lg * 4);
      xs[nf][0] = fast_tanh10(sa[nf][0] * 0.0625f) - (float)mk4.x * 1e9f;
      xs[nf][1] = fast_tanh10(sa[nf][1] * 0.0625f) - (float)mk4.y * 1e9f;
      xs[nf][2] = fast_tanh10(sa[nf][2] * 0.0625f) - (float)mk4.z * 1e9f;
      xs[nf][3] = fast_tanh10(sa[nf][3] * 0.0625f) - (float)mk4.w * 1e9f;
      mx = fmaxf(mx, fmaxf(fmaxf(xs[nf][0], xs[nf][1]), fmaxf(xs[nf][2], xs[nf][3])));
    }
    mx = fmaxf(mx, __shfl_xor(mx, 16));
    mx = fmaxf(mx, __shfl_xor(mx, 32));
    float sm = 0.f;
#pragma unroll
    for (int nf = 0; nf < 8; ++nf)
#pragma unroll
      for (int r = 0; r < 4; ++r) sm += __expf(xs[nf][r] - mx);
    sm += __shfl_xor(sm, 16);
    sm += __shfl_xor(sm, 32);
    float part = logf(sm);
    part += __shfl_xor(part, 1);
    part += __shfl_xor(part, 2);
    part += __shfl_xor(part, 4);
    part += __shfl_xor(part, 8);
    if (l == 0) red[w] = part;
  }
  __syncthreads();
  if (tid == 0) out[b] = -(red[0] + red[1] + red[2] + red[3]);
}

extern "C" void kernel_launch(void* const* d_in, const int* in_sizes, int n_in,
                              void* d_out, int out_size, void* d_ws, size_t ws_size,
                              hipStream_t stream) {
  (void)in_sizes; (void)n_in; (void)out_size; (void)ws_size;
  const float* node_emb  = (const float*)d_in[0];
  const float* graph_emb = (const float*)d_in[1];
  const float* W_target  = (const float*)d_in[2];
  const float* W_global  = (const float*)d_in[3];
  const float* W_K1      = (const float*)d_in[4];
  const float* W_K2      = (const float*)d_in[5];
  const float* W_Q       = (const float*)d_in[6];
  const float* W_V       = (const float*)d_in[7];
  const float* Wq_m      = (const float*)d_in[8];
  const float* Wk_m      = (const float*)d_in[9];
  const float* Wv_m      = (const float*)d_in[10];
  const float* Wo_m      = (const float*)d_in[11];
  const int* targets     = (const int*)d_in[12];
  const int* masks       = (const int*)d_in[13];

  char* p = (char*)d_ws;
  __bf16* KH  = (__bf16*)p; p += (size_t)BB * NN * DD * 2;  // 134 MB
  __bf16* VT  = (__bf16*)p; p += (size_t)BB * DD * NN * 2;  // 134 MB
  __bf16* HO  = (__bf16*)p; p += (size_t)BB * TT * DD * 2;  // 67 MB
  __bf16* Qb  = (__bf16*)p; p += (size_t)BB * TT * DD * 2;  // 67 MB
  __bf16* WTQ = (__bf16*)p; p += 256 * 256 * 2;
  __bf16* WKH = (__bf16*)p; p += 256 * 256 * 2;
  __bf16* WVH = (__bf16*)p; p += 256 * 256 * 2;
  __bf16* WZL = (__bf16*)p; p += 256 * 256 * 2;
  float* WGQT = (float*)p;  p += 256 * 256 * 4;
  float* WQO  = (float*)p;  p += 256 * 256 * 4;
  float* GQ   = (float*)p;  p += (size_t)BB * DD * 4;

  fold1<<<1280, 256, 0, stream>>>(Wq_m, W_target, W_global, Wk_m, W_K1, Wv_m, W_V, W_Q, Wo_m,
                                  WTQ, WGQT, WKH, WVH, WQO);
  fold2<<<256, 256, 0, stream>>>(WQO, W_K2, WZL);
  gq_kernel<<<BB / 8, 256, 0, stream>>>(graph_emb, WGQT, GQ);
  kvq_kernel<<<BB, 512, 0, stream>>>(node_emb, targets, WKH, WVH, WTQ, GQ, KH, VT, Qb);
  attn4_kernel<<<BB * 4, 256, 0, stream>>>(Qb, KH, VT, HO);
  zlog2_kernel<<<BB, 256, 0, stream>>>(node_emb, HO, WZL, masks, (float*)d_out);
}

// Round 20
// 497.792 us; speedup vs baseline: 1.2004x; 1.0437x over previous
//
#include <hip/hip_runtime.h>
#include <hip/hip_bf16.h>

#define BB 2048
#define NN 128
#define DD 256
#define HH 8
#define TT 64

typedef __bf16 bf16x8 __attribute__((ext_vector_type(8)));
typedef float f32x4 __attribute__((ext_vector_type(4)));

static __device__ __forceinline__ f32x4 mfma16(bf16x8 a, bf16x8 b, f32x4 c) {
  return __builtin_amdgcn_mfma_f32_16x16x32_bf16(a, b, c, 0, 0, 0);
}

static __device__ __forceinline__ f32x4 zero4() {
  f32x4 z = {0.f, 0.f, 0.f, 0.f};
  return z;
}

static __device__ __forceinline__ bf16x8 cvt8(const float* p) {
  const float4 x0 = *(const float4*)p;
  const float4 x1 = *(const float4*)(p + 4);
  bf16x8 r;
  r[0] = (__bf16)x0.x; r[1] = (__bf16)x0.y; r[2] = (__bf16)x0.z; r[3] = (__bf16)x0.w;
  r[4] = (__bf16)x1.x; r[5] = (__bf16)x1.y; r[6] = (__bf16)x1.z; r[7] = (__bf16)x1.w;
  return r;
}

static __device__ __forceinline__ unsigned pk2(float a, float b) {
  __bf16 x = (__bf16)a, y = (__bf16)b;
  unsigned short ux, uy;
  __builtin_memcpy(&ux, &x, 2);
  __builtin_memcpy(&uy, &y, 2);
  return (unsigned)ux | ((unsigned)uy << 16);
}

// 10*tanh(y) = 10 - 20/(1+e^{2y}); saturates correctly at +-10.
static __device__ __forceinline__ float fast_tanh10(float y) {
  const float e = __expf(2.f * y);
  return 10.f - 20.f * __builtin_amdgcn_rcpf(1.f + e);
}

// -------- fold1: 5 D x D products, one block per output row --------
__global__ void fold1(const float* __restrict__ Wq_m, const float* __restrict__ W_target,
                      const float* __restrict__ W_global, const float* __restrict__ Wk_m,
                      const float* __restrict__ W_K1, const float* __restrict__ Wv_m,
                      const float* __restrict__ W_V, const float* __restrict__ W_Q,
                      const float* __restrict__ Wo_m,
                      __bf16* __restrict__ WTQ, float* __restrict__ WGQT,
                      __bf16* __restrict__ WKH, __bf16* __restrict__ WVH,
                      float* __restrict__ WQO) {
  const int p = blockIdx.x >> 8;
  const int i = blockIdx.x & 255;
  const int t = threadIdx.x;
  __shared__ float arow[256];
  const float* A;
  const float* Bm;
  if (p == 0)      { A = Wq_m; Bm = W_target; }
  else if (p == 1) { A = Wq_m; Bm = W_global; }
  else if (p == 2) { A = Wk_m; Bm = W_K1; }
  else if (p == 3) { A = Wv_m; Bm = W_V; }
  else             { A = W_Q;  Bm = Wo_m; }
  arow[t] = A[i * 256 + t];
  __syncthreads();
  float acc = 0.f;
  for (int k = 0; k < 256; ++k) acc = fmaf(arow[k], Bm[k * 256 + t], acc);
  if (p == 0)      WTQ[i * 256 + t] = (__bf16)acc;
  else if (p == 1) WGQT[t * 256 + i] = acc;
  else if (p == 2) WKH[i * 256 + t] = (__bf16)acc;
  else if (p == 3) WVH[i * 256 + t] = (__bf16)acc;
  else             WQO[i * 256 + t] = acc;
}

// -------- fold2: WZL[j][i] = sum_d WQO[d][i] * W_K2[d][j]  (bf16) --------
__global__ void fold2(const float* __restrict__ WQO, const float* __restrict__ W_K2,
                      __bf16* __restrict__ WZL) {
  const int j = blockIdx.x;
  const int t = threadIdx.x;
  __shared__ float col[256];
  col[t] = W_K2[t * 256 + j];
  __syncthreads();
  float acc = 0.f;
  for (int d = 0; d < 256; ++d) acc = fmaf(WQO[d * 256 + t], col[d], acc);
  WZL[j * 256 + t] = (__bf16)acc;
}

// -------- gq: 8 b's per block; GQ[b][i] = sum_j WGQT[j][i] * ge[b][j] --------
__global__ void gq_kernel(const float* __restrict__ ge, const float* __restrict__ WGQT,
                          float* __restrict__ GQ) {
  const int b0 = blockIdx.x * 8;
  const int t = threadIdx.x;
  __shared__ float g[8][256];
#pragma unroll
  for (int i = 0; i < 8; ++i) g[i][t] = ge[(b0 + i) * 256 + t];
  __syncthreads();
  float acc[8] = {0.f, 0.f, 0.f, 0.f, 0.f, 0.f, 0.f, 0.f};
  for (int j = 0; j < 256; ++j) {
    const float wv = WGQT[j * 256 + t];
#pragma unroll
    for (int i = 0; i < 8; ++i) acc[i] = fmaf(wv, g[i][j], acc[i]);
  }
#pragma unroll
  for (int i = 0; i < 8; ++i) GQ[(b0 + i) * 256 + t] = acc[i];
}

// -------- kvq (round-9/14 proven config): per b, 512 threads (8 waves). --------
// Stage E[b] bf16 once (+Ebf); K: wave w -> KH cols [32w,32w+32);
// V: wave w -> VT dims [32w,32w+32); Q: wave w -> Q cols with gathered LDS A-rows.
__global__ __launch_bounds__(512)
void kvq_kernel(const float* __restrict__ E, const int* __restrict__ tg,
                const __bf16* __restrict__ WKH, const __bf16* __restrict__ WVH,
                const __bf16* __restrict__ WTQ, const float* __restrict__ GQ,
                __bf16* __restrict__ KH, __bf16* __restrict__ VT,
                __bf16* __restrict__ Qb, __bf16* __restrict__ Ebf) {
  const int b = blockIdx.x;
  const int tid = threadIdx.x;
  const int w = tid >> 6;
  const int l = tid & 63;
  const int lr = l & 15;
  const int lg = l >> 4;
  __shared__ __align__(16) __bf16 Es[128 * 264];
  __shared__ int tgs[64];
  if (tid < 64) tgs[tid] = tg[tid * BB + b];
  const float* Eb = E + (size_t)b * NN * DD;
  __bf16* Ebfb = Ebf + (size_t)b * NN * DD;
#pragma unroll
  for (int it = 0; it < 8; ++it) {
    const int c = it * 512 + tid;
    const int row = c >> 5;
    const int c8 = c & 31;
    const bf16x8 v = cvt8(Eb + row * 256 + c8 * 8);
    *(bf16x8*)&Es[row * 264 + c8 * 8] = v;
    *(bf16x8*)(Ebfb + row * 256 + c8 * 8) = v;
  }
  __syncthreads();

  // ---- K phase: wave w owns cols [32w,32w+32) for all 128 nodes.
  {
    f32x4 acc[8][2];
#pragma unroll
    for (int mf = 0; mf < 8; ++mf)
#pragma unroll
      for (int nf = 0; nf < 2; ++nf) acc[mf][nf] = zero4();
    for (int kk = 0; kk < 8; ++kk) {
      bf16x8 aF[8], bF[2];
#pragma unroll
      for (int mf = 0; mf < 8; ++mf)
        aF[mf] = *(const bf16x8*)&Es[(mf * 16 + lr) * 264 + kk * 32 + lg * 8];
#pragma unroll
      for (int nf = 0; nf < 2; ++nf)
        bF[nf] = *(const bf16x8*)(WKH + (size_t)(w * 32 + nf * 16 + lr) * DD + kk * 32 + lg * 8);
#pragma unroll
      for (int mf = 0; mf < 8; ++mf)
#pragma unroll
        for (int nf = 0; nf < 2; ++nf) acc[mf][nf] = mfma16(aF[mf], bF[nf], acc[mf][nf]);
    }
    __bf16* KHb = KH + (size_t)b * NN * DD;
#pragma unroll
    for (int mf = 0; mf < 8; ++mf)
#pragma unroll
      for (int nf = 0; nf < 2; ++nf)
#pragma unroll
        for (int r = 0; r < 4; ++r)
          KHb[(mf * 16 + lg * 4 + r) * DD + w * 32 + nf * 16 + lr] = (__bf16)acc[mf][nf][r];
  }

  // ---- V phase (transposed): wave w owns dims [32w,32w+32).
  {
    f32x4 acc[2][8];
#pragma unroll
    for (int mf = 0; mf < 2; ++mf)
#pragma unroll
      for (int nf = 0; nf < 8; ++nf) acc[mf][nf] = zero4();
    for (int kk = 0; kk < 8; ++kk) {
      bf16x8 aW[2], bE[8];
#pragma unroll
      for (int mf = 0; mf < 2; ++mf)
        aW[mf] = *(const bf16x8*)(WVH + (size_t)(w * 32 + mf * 16 + lr) * DD + kk * 32 + lg * 8);
#pragma unroll
      for (int nf = 0; nf < 8; ++nf)
        bE[nf] = *(const bf16x8*)&Es[(nf * 16 + lr) * 264 + kk * 32 + lg * 8];
#pragma unroll
      for (int mf = 0; mf < 2; ++mf)
#pragma unroll
        for (int nf = 0; nf < 8; ++nf) acc[mf][nf] = mfma16(aW[mf], bE[nf], acc[mf][nf]);
    }
    __bf16* VTb = VT + (size_t)b * DD * NN;
#pragma unroll
    for (int mf = 0; mf < 2; ++mf)
#pragma unroll
      for (int nf = 0; nf < 8; ++nf)
#pragma unroll
        for (int r = 0; r < 4; ++r)
          VTb[(w * 32 + mf * 16 + lg * 4 + r) * NN + nf * 16 + lr] = (__bf16)acc[mf][nf][r];
  }

  // ---- Q phase: wave w owns cols [32w,32w+32); gathered A-rows from Es (LDS).
  {
    f32x4 acc[4][2];
#pragma unroll
    for (int mf = 0; mf < 4; ++mf)
#pragma unroll
      for (int nf = 0; nf < 2; ++nf) acc[mf][nf] = zero4();
    int rowoff[4];
#pragma unroll
    for (int mf = 0; mf < 4; ++mf) rowoff[mf] = tgs[mf * 16 + lr] * 264;
    for (int kk = 0; kk < 8; ++kk) {
      bf16x8 aF[4], bF[2];
#pragma unroll
      for (int mf = 0; mf < 4; ++mf)
        aF[mf] = *(const bf16x8*)&Es[rowoff[mf] + kk * 32 + lg * 8];
#pragma unroll
      for (int nf = 0; nf < 2; ++nf)
        bF[nf] = *(const bf16x8*)(WTQ + (size_t)(w * 32 + nf * 16 + lr) * DD + kk * 32 + lg * 8);
#pragma unroll
      for (int mf = 0; mf < 4; ++mf)
#pragma unroll
        for (int nf = 0; nf < 2; ++nf) acc[mf][nf] = mfma16(aF[mf], bF[nf], acc[mf][nf]);
    }
#pragma unroll
    for (int nf = 0; nf < 2; ++nf) {
      const int col = w * 32 + nf * 16 + lr;
      const float g = GQ[b * DD + col];
#pragma unroll
      for (int mf = 0; mf < 4; ++mf)
#pragma unroll
        for (int r = 0; r < 4; ++r)
          Qb[((size_t)b * TT + mf * 16 + lg * 4 + r) * DD + col] = (__bf16)(acc[mf][nf][r] + g);
    }
  }
}

// -------- attn4: per (b, head-pair), XCD-clustered. Stage KH/VT slices in LDS --------
// once (1 barrier); aq hoisted above staging. QK swapped from KHs, P via per-wave
// LDS buf (same-wave in-order), PV from VTs. Round-9 proven inner structure.
__global__ __launch_bounds__(256)
void attn4_kernel(const __bf16* __restrict__ Qb, const __bf16* __restrict__ KH,
                  const __bf16* __restrict__ VT, __bf16* __restrict__ HO) {
  const int j = (blockIdx.x & 7) * ((BB * 4) / 8) + (blockIdx.x >> 3);
  const int b = j >> 2;
  const int c0 = (j & 3) * 64;  // dim window of this head pair
  const int tid = threadIdx.x;
  const int w = tid >> 6;
  const int l = tid & 63;
  const int lr = l & 15;
  const int lg = l >> 4;
  const int T0 = w * 16;

  __shared__ __align__(16) __bf16 KHs[128 * 72];  // [node][64 dims]
  __shared__ __align__(16) __bf16 VTs[64 * 136];  // [dim][128 nodes]
  __shared__ __align__(16) __bf16 Ps[4][16 * 136];

  const __bf16* KHb = KH + (size_t)b * NN * DD;
  const __bf16* VTb = VT + (size_t)b * DD * NN;

  // hoist both heads' Q fragments; loads overlap the staging below.
  bf16x8 aq[2];
#pragma unroll
  for (int h = 0; h < 2; ++h)
    aq[h] = *(const bf16x8*)(Qb + ((size_t)b * TT + T0 + lr) * DD + c0 + h * 32 + lg * 8);

#pragma unroll
  for (int it = 0; it < 4; ++it) {  // KHs: 128 rows x 8 chunks
    const int c = it * 256 + tid;
    const int row = c >> 3;
    const int c8 = c & 7;
    *(bf16x8*)&KHs[row * 72 + c8 * 8] = *(const bf16x8*)(KHb + (size_t)row * DD + c0 + c8 * 8);
  }
#pragma unroll
  for (int it = 0; it < 4; ++it) {  // VTs: 64 rows x 16 chunks
    const int c = it * 256 + tid;
    const int row = c >> 4;
    const int c8 = c & 15;
    *(bf16x8*)&VTs[row * 136 + c8 * 8] =
        *(const bf16x8*)(VTb + (size_t)(c0 + row) * NN + c8 * 8);
  }
  __syncthreads();

  __bf16* myp = Ps[w];
  __bf16* HOb = HO + (size_t)b * TT * DD + c0;

#pragma unroll
  for (int h = 0; h < 2; ++h) {
    // QK swapped: lane holds S[node = nf*16+lg*4+r][t = T0+lr]
    f32x4 s[8];
#pragma unroll
    for (int nf = 0; nf < 8; ++nf)
      s[nf] = mfma16(*(const bf16x8*)&KHs[(nf * 16 + lr) * 72 + h * 32 + lg * 8], aq[h], zero4());

    float mx = -1e30f;
#pragma unroll
    for (int nf = 0; nf < 8; ++nf)
#pragma unroll
      for (int r = 0; r < 4; ++r) mx = fmaxf(mx, s[nf][r]);
    mx = fmaxf(mx, __shfl_xor(mx, 16));
    mx = fmaxf(mx, __shfl_xor(mx, 32));

    float sm = 0.f;
    uint2 evp[8];
#pragma unroll
    for (int nf = 0; nf < 8; ++nf) {
      const float e0 = __expf((s[nf][0] - mx) * 0.17677669529663687f);
      const float e1 = __expf((s[nf][1] - mx) * 0.17677669529663687f);
      const float e2 = __expf((s[nf][2] - mx) * 0.17677669529663687f);
      const float e3 = __expf((s[nf][3] - mx) * 0.17677669529663687f);
      sm += (e0 + e1) + (e2 + e3);
      evp[nf].x = pk2(e0, e1);
      evp[nf].y = pk2(e2, e3);
    }
    sm += __shfl_xor(sm, 16);
    sm += __shfl_xor(sm, 32);

    // P row t-local=lr: nodes nf*16 + lg*4 .. +4 (same-wave in-order DS)
#pragma unroll
    for (int nf = 0; nf < 8; ++nf)
      *(uint2*)&myp[lr * 136 + nf * 16 + lg * 4] = evp[nf];

    // PV: A = P rows (LDS), B = VTs dim-rows (LDS)
    f32x4 o0 = zero4(), o1 = zero4();
#pragma unroll
    for (int kk = 0; kk < 4; ++kk) {
      const bf16x8 ap = *(const bf16x8*)&myp[lr * 136 + kk * 32 + lg * 8];
      o0 = mfma16(ap, *(const bf16x8*)&VTs[(h * 32 + lr) * 136 + kk * 32 + lg * 8], o0);
      o1 = mfma16(ap, *(const bf16x8*)&VTs[(h * 32 + 16 + lr) * 136 + kk * 32 + lg * 8], o1);
    }
#pragma unroll
    for (int r = 0; r < 4; ++r) {
      const float inv = __builtin_amdgcn_rcpf(__shfl(sm, lg * 4 + r));
      HOb[(size_t)(T0 + lg * 4 + r) * DD + h * 32 + lr] = (__bf16)(o0[r] * inv);
      HOb[(size_t)(T0 + lg * 4 + r) * DD + h * 32 + 16 + lr] = (__bf16)(o1[r] * inv);
    }
  }
}

// -------- zlog2: per b. Z = HO @ WZL^T -> Zs; logits swapped (lane owns t-row) --------
__global__ __launch_bounds__(256)
void zlog2_kernel(const __bf16* __restrict__ Ebf, const __bf16* __restrict__ HO,
                  const __bf16* __restrict__ WZL, const int* __restrict__ MK,
                  float* __restrict__ out) {
  const int b = blockIdx.x;
  const int tid = threadIdx.x;
  const int w = tid >> 6;
  const int l = tid & 63;
  const int lr = l & 15;
  const int lg = l >> 4;
  const int T0 = w * 16;
  __shared__ __align__(16) __bf16 Zs[64 * 264];
  __shared__ float red[4];

  const __bf16* Eb = Ebf + (size_t)b * NN * DD;
  const __bf16* HOb = HO + (size_t)b * TT * DD;

  // Z GEMM: wave w owns cols [64w,64w+64) for all 64 t-rows.
  {
    f32x4 acc[4][4];
#pragma unroll
    for (int mf = 0; mf < 4; ++mf)
#pragma unroll
      for (int nf = 0; nf < 4; ++nf) acc[mf][nf] = zero4();
    for (int kk = 0; kk < 8; ++kk) {
      bf16x8 aF[4], bF[4];
#pragma unroll
      for (int mf = 0; mf < 4; ++mf)
        aF[mf] = *(const bf16x8*)(HOb + (size_t)(mf * 16 + lr) * DD + kk * 32 + lg * 8);
#pragma unroll
      for (int nf = 0; nf < 4; ++nf)
        bF[nf] = *(const bf16x8*)(WZL + (size_t)(w * 64 + nf * 16 + lr) * DD + kk * 32 + lg * 8);
#pragma unroll
      for (int mf = 0; mf < 4; ++mf)
#pragma unroll
        for (int nf = 0; nf < 4; ++nf) acc[mf][nf] = mfma16(aF[mf], bF[nf], acc[mf][nf]);
    }
#pragma unroll
    for (int mf = 0; mf < 4; ++mf)
#pragma unroll
      for (int nf = 0; nf < 4; ++nf)
#pragma unroll
        for (int r = 0; r < 4; ++r)
          Zs[(mf * 16 + lg * 4 + r) * 264 + w * 64 + nf * 16 + lr] = (__bf16)acc[mf][nf][r];
  }
  __syncthreads();

  // logits swapped: A = Ebf nodes, B = Zs t-rows. Lane owns t=T0+lr.
  {
    f32x4 sa[8];
#pragma unroll
    for (int nf = 0; nf < 8; ++nf) sa[nf] = zero4();
    for (int kk = 0; kk < 8; ++kk) {
      const bf16x8 bZ = *(const bf16x8*)&Zs[(T0 + lr) * 264 + kk * 32 + lg * 8];
#pragma unroll
      for (int nf = 0; nf < 8; ++nf) {
        const bf16x8 aE = *(const bf16x8*)(Eb + (size_t)(nf * 16 + lr) * DD + kk * 32 + lg * 8);
        sa[nf] = mfma16(aE, bZ, sa[nf]);
      }
    }
    const int t = T0 + lr;
    float xs[8][4];
    float mx = -3e38f;
#pragma unroll
    for (int nf = 0; nf < 8; ++nf) {
      const int4 mk4 = *(const int4*)(MK + ((size_t)t * BB + b) * NN + nf * 16 + lg * 4);
      xs[nf][0] = fast_tanh10(sa[nf][0] * 0.0625f) - (float)mk4.x * 1e9f;
      xs[nf][1] = fast_tanh10(sa[nf][1] * 0.0625f) - (float)mk4.y * 1e9f;
      xs[nf][2] = fast_tanh10(sa[nf][2] * 0.0625f) - (float)mk4.z * 1e9f;
      xs[nf][3] = fast_tanh10(sa[nf][3] * 0.0625f) - (float)mk4.w * 1e9f;
      mx = fmaxf(mx, fmaxf(fmaxf(xs[nf][0], xs[nf][1]), fmaxf(xs[nf][2], xs[nf][3])));
    }
    mx = fmaxf(mx, __shfl_xor(mx, 16));
    mx = fmaxf(mx, __shfl_xor(mx, 32));
    float sm = 0.f;
#pragma unroll
    for (int nf = 0; nf < 8; ++nf)
#pragma unroll
      for (int r = 0; r < 4; ++r) sm += __expf(xs[nf][r] - mx);
    sm += __shfl_xor(sm, 16);
    sm += __shfl_xor(sm, 32);
    float part = logf(sm);
    part += __shfl_xor(part, 1);
    part += __shfl_xor(part, 2);
    part += __shfl_xor(part, 4);
    part += __shfl_xor(part, 8);
    if (l == 0) red[w] = part;
  }
  __syncthreads();
  if (tid == 0) out[b] = -(red[0] + red[1] + red[2] + red[3]);
}

extern "C" void kernel_launch(void* const* d_in, const int* in_sizes, int n_in,
                              void* d_out, int out_size, void* d_ws, size_t ws_size,
                              hipStream_t stream) {
  (void)in_sizes; (void)n_in; (void)out_size; (void)ws_size;
  const float* node_emb  = (const float*)d_in[0];
  const float* graph_emb = (const float*)d_in[1];
  const float* W_target  = (const float*)d_in[2];
  const float* W_global  = (const float*)d_in[3];
  const float* W_K1      = (const float*)d_in[4];
  const float* W_K2      = (const float*)d_in[5];
  const float* W_Q       = (const float*)d_in[6];
  const float* W_V       = (const float*)d_in[7];
  const float* Wq_m      = (const float*)d_in[8];
  const float* Wk_m      = (const float*)d_in[9];
  const float* Wv_m      = (const float*)d_in[10];
  const float* Wo_m      = (const float*)d_in[11];
  const int* targets     = (const int*)d_in[12];
  const int* masks       = (const int*)d_in[13];

  char* p = (char*)d_ws;
  __bf16* Ebf = (__bf16*)p; p += (size_t)BB * NN * DD * 2;  // 134 MB
  __bf16* KH  = (__bf16*)p; p += (size_t)BB * NN * DD * 2;  // 134 MB
  __bf16* VT  = (__bf16*)p; p += (size_t)BB * DD * NN * 2;  // 134 MB
  __bf16* HO  = (__bf16*)p; p += (size_t)BB * TT * DD * 2;  // 67 MB
  __bf16* Qb  = (__bf16*)p; p += (size_t)BB * TT * DD * 2;  // 67 MB
  __bf16* WTQ = (__bf16*)p; p += 256 * 256 * 2;
  __bf16* WKH = (__bf16*)p; p += 256 * 256 * 2;
  __bf16* WVH = (__bf16*)p; p += 256 * 256 * 2;
  __bf16* WZL = (__bf16*)p; p += 256 * 256 * 2;
  float* WGQT = (float*)p;  p += 256 * 256 * 4;
  float* WQO  = (float*)p;  p += 256 * 256 * 4;
  float* GQ   = (float*)p;  p += (size_t)BB * DD * 4;

  fold1<<<1280, 256, 0, stream>>>(Wq_m, W_target, W_global, Wk_m, W_K1, Wv_m, W_V, W_Q, Wo_m,
                                  WTQ, WGQT, WKH, WVH, WQO);
  fold2<<<256, 256, 0, stream>>>(WQO, W_K2, WZL);
  gq_kernel<<<BB / 8, 256, 0, stream>>>(graph_emb, WGQT, GQ);
  kvq_kernel<<<BB, 512, 0, stream>>>(node_emb, targets, WKH, WVH, WTQ, GQ, KH, VT, Qb, Ebf);
  attn4_kernel<<<BB * 4, 256, 0, stream>>>(Qb, KH, VT, HO);
  zlog2_kernel<<<BB, 256, 0, stream>>>(Ebf, HO, WZL, masks, (float*)d_out);
}